// Round 10
// baseline (98.132 us; speedup 1.0000x reference)
//
#include <hip/hip_runtime.h>

// AttentionConvFull: grouped 1x1 QKV + 5x5 per-channel local attention, FUSED.
// B=4, H=W=56, C=OC=256, G=8, Cg=32, K=5, pad=2.
//
// One kernel, one block per (batch, 8x8 tile, group), 256 threads
// (c = tid&31 channel, p0 = tid>>5 pixel column/slice).
//   Phase A: wq row -> 32 regs; q for 8 interior pixels (x rows via broadcast
//            global loads); wq dies. Then wk/wv -> 64 regs.
//   Phase B: k,v for 144 halo pixels -> LDS (x rows broadcast-loaded).
//   Phase C: row-streaming attention: each halo row's 5 k/v read once,
//            scattered into up to 5 pixels; native exp2 (q pre-scaled by
//            log2e) + rcp; single-pass softmax (logits bounded, f32-safe).
//
// R10 EXPERIMENT: __launch_bounds__(256) with NO min-waves arg.
// R9 evidence: (256,2) kernels pin OccupancyPercent at ~25% (= 2 waves/EU)
// even when VGPR(80) and LDS(36.9KB) permit 4 blocks/CU -> hypothesis: the
// 2nd arg acts as a waves/EU cap, not just an allocator hint. This kernel is
// latency-bound (208 broadcast-load rounds/thread); residency is the lever.
//
// Register-budget law (R1-R8): VGPR cap = 256/N for __launch_bounds__(256,N);
// NO launch_bounds at all defaults to 1024-wg and caps at 64 (R4 spills).
// Occupancy bands (VGPR): <=64: 8 waves/SIMD; 65-128: 4; 129-256: 2.
// Phase-B peak liveness ~110 must stay <=128 (no extra unroll!).

constexpr int TB = 4, TH = 56, TW = 56, TC = 256;
constexpr int G  = 8, CG = 32, PAD = 2;
constexpr int TILE = 8;
constexpr int HT = TILE + 2 * PAD;   // 12
constexpr int NT = TH / TILE;        // 7
constexpr int NPIX_HALO = HT * HT;   // 144
constexpr float LOG2E = 1.44269504088896340736f;

__global__ __launch_bounds__(256)
void fused_attn_conv_kernel(const float* __restrict__ x,
                            const float* __restrict__ wq,
                            const float* __restrict__ wk,
                            const float* __restrict__ wv,
                            const float* __restrict__ rel,
                            const float* __restrict__ qemb,
                            float* __restrict__ out) {
    __shared__ float ks[NPIX_HALO][CG];   // 18 KB
    __shared__ float vs[NPIX_HALO][CG];   // 18 KB

    const int bid  = blockIdx.x;
    const int g    = bid & 7;
    const int tile = bid >> 3;
    const int tj   = tile % NT;
    const int ti   = (tile / NT) % NT;
    const int b    = tile / (NT * NT);

    const int t  = threadIdx.x;
    const int c  = t & 31;
    const int p0 = t >> 5;

    const int oc = g * CG + c;           // global out-channel
    const int h0 = ti * TILE - PAD, w0 = tj * TILE - PAD;

    // ---- Phase A: q for this thread's 8 interior pixels (column p0).
    //      wq row lives only here (32 regs), then dies before wk/wv load.
    float qreg[8];
    {
        float wqr[CG];
        const float4* wqp = (const float4*)(wq + (size_t)oc * CG);
#pragma unroll
        for (int i = 0; i < CG / 4; ++i) {
            float4 a = wqp[i];
            wqr[4*i+0]=a.x; wqr[4*i+1]=a.y; wqr[4*i+2]=a.z; wqr[4*i+3]=a.w;
        }
        const float qe = qemb[oc];
#pragma unroll 1
        for (int ii = 0; ii < 8; ++ii) {
            const int gh = ti * TILE + ii, gw = tj * TILE + p0;
            const float4* xp = (const float4*)(x + (((size_t)b * TH + gh) * TW + gw) * TC + g * CG);
            float aq = qe;
#pragma unroll
            for (int i = 0; i < CG / 4; ++i) {
                const float4 xv = xp[i];   // broadcast: 32 lanes same address
                aq = fmaf(wqr[4*i+0], xv.x, aq);
                aq = fmaf(wqr[4*i+1], xv.y, aq);
                aq = fmaf(wqr[4*i+2], xv.z, aq);
                aq = fmaf(wqr[4*i+3], xv.w, aq);
            }
            qreg[ii] = aq * LOG2E;         // pre-scaled for exp2 softmax
        }
    }

    // ---- Phase B: k,v for 18 halo pixels per thread-slice -> LDS.
    {
        float wkr[CG], wvr[CG];
        const float4* wkp = (const float4*)(wk + (size_t)oc * CG);
        const float4* wvp = (const float4*)(wv + (size_t)oc * CG);
#pragma unroll
        for (int i = 0; i < CG / 4; ++i) {
            float4 bb = wkp[i], cc = wvp[i];
            wkr[4*i+0]=bb.x; wkr[4*i+1]=bb.y; wkr[4*i+2]=bb.z; wkr[4*i+3]=bb.w;
            wvr[4*i+0]=cc.x; wvr[4*i+1]=cc.y; wvr[4*i+2]=cc.z; wvr[4*i+3]=cc.w;
        }
#pragma unroll 1
        for (int it = 0; it < NPIX_HALO / 8; ++it) {
            const int hp = it * 8 + p0;
            const int hi = hp / HT, hj = hp % HT;
            const int gh = h0 + hi, gw = w0 + hj;
            float ak = 0.f, av = 0.f;
            if (gh >= 0 && gh < TH && gw >= 0 && gw < TW) {
                const float4* xp = (const float4*)(x + (((size_t)b * TH + gh) * TW + gw) * TC + g * CG);
#pragma unroll
                for (int i = 0; i < CG / 4; ++i) {
                    const float4 xv = xp[i];   // broadcast within half-wave
                    ak = fmaf(wkr[4*i+0], xv.x, ak); av = fmaf(wvr[4*i+0], xv.x, av);
                    ak = fmaf(wkr[4*i+1], xv.y, ak); av = fmaf(wvr[4*i+1], xv.y, av);
                    ak = fmaf(wkr[4*i+2], xv.z, ak); av = fmaf(wvr[4*i+2], xv.z, av);
                    ak = fmaf(wkr[4*i+3], xv.w, ak); av = fmaf(wvr[4*i+3], xv.w, av);
                }
            }
            ks[hp][c] = ak;    // OOB rows stay 0: matches zero-padded conv
            vs[hp][c] = av;
        }
    }

    // rel row for this channel (global, L2-hot; compiler-managed regs)
    const float* rp = rel + (size_t)oc * 25;
    float relr[25];
#pragma unroll
    for (int i = 0; i < 25; ++i) relr[i] = rp[i];

    __syncthreads();

    // ---- Phase C: row-streaming attention.
    float s_[8], a_[8];
#pragma unroll
    for (int ii = 0; ii < 8; ++ii) { s_[ii] = 0.f; a_[ii] = 0.f; }

#pragma unroll
    for (int h = 0; h < HT; ++h) {
        float kr[5], vr[5];
#pragma unroll
        for (int j = 0; j < 5; ++j) {
            kr[j] = ks[h * HT + p0 + j][c];
            vr[j] = vs[h * HT + p0 + j][c];
        }
#pragma unroll
        for (int ii = 0; ii < 8; ++ii) {
            const int di = h - ii;               // compile-time after unroll
            if (di >= 0 && di < 5) {
                const float qv = qreg[ii];
#pragma unroll
                for (int j = 0; j < 5; ++j) {
                    const float e = __builtin_amdgcn_exp2f(qv * (kr[j] + relr[di * 5 + j]));
                    s_[ii] += e;
                    a_[ii] = fmaf(e, vr[j], a_[ii]);
                }
            }
        }
    }

#pragma unroll
    for (int ii = 0; ii < 8; ++ii) {
        const int gh = ti * TILE + ii, gw = tj * TILE + p0;
        out[(((size_t)b * TH + gh) * TW + gw) * TC + g * CG + c] =
            a_[ii] * __builtin_amdgcn_rcpf(s_[ii]);
    }
}

extern "C" void kernel_launch(void* const* d_in, const int* in_sizes, int n_in,
                              void* d_out, int out_size, void* d_ws, size_t ws_size,
                              hipStream_t stream) {
    const float* x    = (const float*)d_in[0];
    const float* wq   = (const float*)d_in[1];
    const float* wk   = (const float*)d_in[2];
    const float* wv   = (const float*)d_in[3];
    const float* rel  = (const float*)d_in[4];
    const float* qemb = (const float*)d_in[5];
    float* out = (float*)d_out;

    const int nblocks = TB * NT * NT * G;   // 4*7*7*8 = 1568
    hipLaunchKernelGGL(fused_attn_conv_kernel, dim3(nblocks), dim3(256), 0, stream,
                       x, wq, wk, wv, rel, qemb, out);
}

// Round 11
// 56.862 us; speedup vs baseline: 1.7258x; 1.7258x over previous
//
#include <hip/hip_runtime.h>

// AttentionConvFull: grouped 1x1 QKV + 5x5 per-channel local attention, FUSED.
// B=4, H=W=56, C=OC=256, G=8, Cg=32, K=5, pad=2.
//
// One block per (batch, 8x8 tile, group); 256 threads (c=tid&31, p0=tid>>5).
//   Stage:   x halo (12x12 px, 32 ch) -> xs LDS, coalesced float4 (~4.5
//            rounds/thread). OOB pixels zeroed (matches zero-padded conv).
//   Phase A: wq row (32 regs, phase-local) -> q for 8 interior pixels from
//            xs broadcast reads; q pre-scaled by log2e. wq dies.
//   Phase B: wk/wv rows (64 regs) -> k,v for 144 halo pixels from xs reads;
//            k OVERWRITES xs IN PLACE (pixel row read + written by the same
//            half-wave; per-wave in-order DS ops => race-free, no barrier),
//            v -> vs. LDS total stays 36.9 KB (4-blocks/CU capable).
//   Phase C: row-streaming attention: each halo row's 5 k/v read once,
//            scattered into up to 5 output pixels; native exp2 + rcp;
//            single-pass softmax (logits bounded ~|25|, f32-safe).
// Only 3 barriers total (stage->A, A->B, B->C).
//
// WHY: R8-R10 showed the compute phases' ~208 global broadcast-load rounds
// per thread are latency-unhideable (VALUBusy 24-32%, FETCH tiny, no spill).
// LDS-staging x converts them to ~64cy LDS broadcasts.
//
// Register law (R1-R10): cap = 256/N VGPR for __launch_bounds__(256,N); no
// bounds => 64 (R4) ; no min-arg => allocator floats high (R10: 132 -> worse).
// HW wave/SIMD bands: <=64:8, <=128:4, <=170:3, <=256:2. Keep peak <=128.
// Spill signature: VGPR==cap AND WRITE_SIZE >> logical bytes.

constexpr int TB = 4, TH = 56, TW = 56, TC = 256;
constexpr int G  = 8, CG = 32, PAD = 2;
constexpr int TILE = 8;
constexpr int HT = TILE + 2 * PAD;   // 12
constexpr int NT = TH / TILE;        // 7
constexpr int NPIX_HALO = HT * HT;   // 144
constexpr float LOG2E = 1.44269504088896340736f;

__global__ __launch_bounds__(256, 2)
void fused_attn_conv_kernel(const float* __restrict__ x,
                            const float* __restrict__ wq,
                            const float* __restrict__ wk,
                            const float* __restrict__ wv,
                            const float* __restrict__ rel,
                            const float* __restrict__ qemb,
                            float* __restrict__ out) {
    __shared__ float xs[NPIX_HALO][CG];   // 18 KB: x halo, then k (in place)
    __shared__ float vs[NPIX_HALO][CG];   // 18 KB: v

    const int bid  = blockIdx.x;
    const int g    = bid & 7;
    const int tile = bid >> 3;
    const int tj   = tile % NT;
    const int ti   = (tile / NT) % NT;
    const int b    = tile / (NT * NT);

    const int t  = threadIdx.x;
    const int c  = t & 31;
    const int p0 = t >> 5;

    const int oc = g * CG + c;           // global out-channel
    const int h0 = ti * TILE - PAD, w0 = tj * TILE - PAD;

    // ---- Stage: x halo -> xs, coalesced float4 (1152 float4 over 256 thr).
#pragma unroll
    for (int r = 0; r < 5; ++r) {
        const int f = t + r * 256;
        if (f < NPIX_HALO * CG / 4) {
            const int hp = f >> 3, c4 = f & 7;        // 8 float4 per pixel
            const int hi = hp / HT, hj = hp % HT;
            const int gh = h0 + hi, gw = w0 + hj;
            float4 val = make_float4(0.f, 0.f, 0.f, 0.f);
            if (gh >= 0 && gh < TH && gw >= 0 && gw < TW)
                val = *(const float4*)(x + (((size_t)b * TH + gh) * TW + gw) * TC
                                         + g * CG + c4 * 4);
            *(float4*)&xs[hp][c4 * 4] = val;
        }
    }

    __syncthreads();   // stage -> A

    // ---- Phase A: q for this thread's 8 interior pixels (column p0).
    float qreg[8];
    {
        float wqr[CG];
        const float4* wqp = (const float4*)(wq + (size_t)oc * CG);
#pragma unroll
        for (int i = 0; i < CG / 4; ++i) {
            float4 a = wqp[i];
            wqr[4*i+0]=a.x; wqr[4*i+1]=a.y; wqr[4*i+2]=a.z; wqr[4*i+3]=a.w;
        }
        const float qe = qemb[oc];
#pragma unroll 1
        for (int ii = 0; ii < 8; ++ii) {
            const int hp = (ii + PAD) * HT + (p0 + PAD);
            const float4* xp = (const float4*)&xs[hp][0];
            float aq = qe;
#pragma unroll
            for (int i = 0; i < CG / 4; ++i) {
                const float4 xv = xp[i];   // LDS broadcast within half-wave
                aq = fmaf(wqr[4*i+0], xv.x, aq);
                aq = fmaf(wqr[4*i+1], xv.y, aq);
                aq = fmaf(wqr[4*i+2], xv.z, aq);
                aq = fmaf(wqr[4*i+3], xv.w, aq);
            }
            qreg[ii] = aq * LOG2E;         // pre-scaled for exp2 softmax
        }
    }

    __syncthreads();   // A reads done before B overwrites xs

    // ---- Phase B: k,v for all 144 halo pixels; k overwrites xs in place.
    //      Round it: half-wave group p0 owns pixel hp=it*8+p0 exclusively
    //      (reads its full row, writes its row) -> no barrier needed.
    {
        float wkr[CG], wvr[CG];
        const float4* wkp = (const float4*)(wk + (size_t)oc * CG);
        const float4* wvp = (const float4*)(wv + (size_t)oc * CG);
#pragma unroll
        for (int i = 0; i < CG / 4; ++i) {
            float4 bb = wkp[i], cc = wvp[i];
            wkr[4*i+0]=bb.x; wkr[4*i+1]=bb.y; wkr[4*i+2]=bb.z; wkr[4*i+3]=bb.w;
            wvr[4*i+0]=cc.x; wvr[4*i+1]=cc.y; wvr[4*i+2]=cc.z; wvr[4*i+3]=cc.w;
        }
#pragma unroll 1
        for (int it = 0; it < NPIX_HALO / 8; ++it) {
            const int hp = it * 8 + p0;
            const float4* xp = (const float4*)&xs[hp][0];
            float ak = 0.f, av = 0.f;
#pragma unroll
            for (int i = 0; i < CG / 4; ++i) {
                const float4 xv = xp[i];   // LDS broadcast; OOB rows are zeros
                ak = fmaf(wkr[4*i+0], xv.x, ak); av = fmaf(wvr[4*i+0], xv.x, av);
                ak = fmaf(wkr[4*i+1], xv.y, ak); av = fmaf(wvr[4*i+1], xv.y, av);
                ak = fmaf(wkr[4*i+2], xv.z, ak); av = fmaf(wvr[4*i+2], xv.z, av);
                ak = fmaf(wkr[4*i+3], xv.w, ak); av = fmaf(wvr[4*i+3], xv.w, av);
            }
            xs[hp][c] = ak;    // in-place k (after all reads of this row)
            vs[hp][c] = av;
        }
    }

    // rel row for this channel (global, L2-hot); overlaps with barrier wait
    const float* rp = rel + (size_t)oc * 25;
    float relr[25];
#pragma unroll
    for (int i = 0; i < 25; ++i) relr[i] = rp[i];

    __syncthreads();   // B -> C

    // ---- Phase C: row-streaming attention (xs now holds k).
    float s_[8], a_[8];
#pragma unroll
    for (int ii = 0; ii < 8; ++ii) { s_[ii] = 0.f; a_[ii] = 0.f; }

#pragma unroll
    for (int h = 0; h < HT; ++h) {
        float kr[5], vr[5];
#pragma unroll
        for (int j = 0; j < 5; ++j) {
            kr[j] = xs[h * HT + p0 + j][c];
            vr[j] = vs[h * HT + p0 + j][c];
        }
#pragma unroll
        for (int ii = 0; ii < 8; ++ii) {
            const int di = h - ii;               // compile-time after unroll
            if (di >= 0 && di < 5) {
                const float qv = qreg[ii];
#pragma unroll
                for (int j = 0; j < 5; ++j) {
                    const float e = __builtin_amdgcn_exp2f(qv * (kr[j] + relr[di * 5 + j]));
                    s_[ii] += e;
                    a_[ii] = fmaf(e, vr[j], a_[ii]);
                }
            }
        }
    }

#pragma unroll
    for (int ii = 0; ii < 8; ++ii) {
        const int gh = ti * TILE + ii, gw = tj * TILE + p0;
        out[(((size_t)b * TH + gh) * TW + gw) * TC + g * CG + c] =
            a_[ii] * __builtin_amdgcn_rcpf(s_[ii]);
    }
}

extern "C" void kernel_launch(void* const* d_in, const int* in_sizes, int n_in,
                              void* d_out, int out_size, void* d_ws, size_t ws_size,
                              hipStream_t stream) {
    const float* x    = (const float*)d_in[0];
    const float* wq   = (const float*)d_in[1];
    const float* wk   = (const float*)d_in[2];
    const float* wv   = (const float*)d_in[3];
    const float* rel  = (const float*)d_in[4];
    const float* qemb = (const float*)d_in[5];
    float* out = (float*)d_out;

    const int nblocks = TB * NT * NT * G;   // 4*7*7*8 = 1568
    hipLaunchKernelGGL(fused_attn_conv_kernel, dim3(nblocks), dim3(256), 0, stream,
                       x, wq, wk, wv, rel, qemb, out);
}

// Round 12
// 52.867 us; speedup vs baseline: 1.8562x; 1.0756x over previous
//
#include <hip/hip_runtime.h>

// AttentionConvFull: grouped 1x1 QKV + 5x5 per-channel local attention, FUSED.
// B=4, H=W=56, C=OC=256, G=8, Cg=32, K=5, pad=2.
//
// One block per (batch, 8x8 tile, group); 256 threads (c=tid&31, p0=tid>>5).
//   Stage:   x halo (12x12 px, 32 ch) -> xs LDS, coalesced float4, OOB zeroed.
//   Merged QKV pass (single loop, 18 iters): wq+wk+wv = 96 regs (R8-measured
//            VGPR 112 for this loop shape); per halo pixel: 8 b128 xs reads,
//            3 interleaved FMA chains. k,v packed to bf16x2 in ONE u32 and
//            OVERWRITE xs in place (each row's only reader+writer is its
//            owning half-wave, read-then-write order => race-free). q written
//            (pre-scaled by log2e) to qs for interior pixels only.
//   Phase C: row-streaming attention; k,v unpacked from one b32 per element
//            (u<<16 = k bits, u&0xffff0000 = v bits); native exp2 + rcp;
//            single-pass softmax (logits bounded, f32-safe).
// LDS: xs 18KB + qs 8KB = 26.6KB. 2 barriers total.
//
// WHY (R11 counters): LDS-pipe-bound: 208 b128 broadcasts/wave x 12cyc x
// 24.5 waves/CU ~ 35us > VALU ~28us. This cuts LDS instrs ~33% (merge kills
// A's 64 b128; packing halves C reads + B writes) and LDS bytes 36.9->26.6KB.
// Precision: bf16 k,v adds ~3e-3 absmax; threshold 5.7e-2, current 3.9e-3.
//
// Register law (R1-R10): cap = 256/N for __launch_bounds__(256,N); no bounds
// => 64 (spills); no min-arg => allocator floats >128 (worse band). Spill
// signature: VGPR==cap AND WRITE_SIZE >> logical bytes (12.5MB here).

constexpr int TB = 4, TH = 56, TW = 56, TC = 256;
constexpr int G  = 8, CG = 32, PAD = 2;
constexpr int TILE = 8;
constexpr int HT = TILE + 2 * PAD;   // 12
constexpr int NT = TH / TILE;        // 7
constexpr int NPIX_HALO = HT * HT;   // 144
constexpr float LOG2E = 1.44269504088896340736f;

__global__ __launch_bounds__(256, 2)
void fused_attn_conv_kernel(const float* __restrict__ x,
                            const float* __restrict__ wq,
                            const float* __restrict__ wk,
                            const float* __restrict__ wv,
                            const float* __restrict__ rel,
                            const float* __restrict__ qemb,
                            float* __restrict__ out) {
    __shared__ float xs[NPIX_HALO][CG];    // 18 KB: x halo, then packed bf16(k,v)
    __shared__ float qs[TILE * TILE][CG];  // 8 KB: q*log2e for interior pixels

    const int bid  = blockIdx.x;
    const int g    = bid & 7;
    const int tile = bid >> 3;
    const int tj   = tile % NT;
    const int ti   = (tile / NT) % NT;
    const int b    = tile / (NT * NT);

    const int t  = threadIdx.x;
    const int c  = t & 31;
    const int p0 = t >> 5;

    const int oc = g * CG + c;           // global out-channel
    const int h0 = ti * TILE - PAD, w0 = tj * TILE - PAD;

    // ---- Stage: x halo -> xs, coalesced float4 (1152 float4 over 256 thr).
#pragma unroll
    for (int r = 0; r < 5; ++r) {
        const int f = t + r * 256;
        if (f < NPIX_HALO * CG / 4) {
            const int hp = f >> 3, c4 = f & 7;        // 8 float4 per pixel
            const int hi = hp / HT, hj = hp % HT;
            const int gh = h0 + hi, gw = w0 + hj;
            float4 val = make_float4(0.f, 0.f, 0.f, 0.f);
            if (gh >= 0 && gh < TH && gw >= 0 && gw < TW)
                val = *(const float4*)(x + (((size_t)b * TH + gh) * TW + gw) * TC
                                         + g * CG + c4 * 4);
            *(float4*)&xs[hp][c4 * 4] = val;
        }
    }

    __syncthreads();   // stage -> merged pass

    // ---- Merged QKV pass over all 144 halo pixels.
    {
        float wqr[CG], wkr[CG], wvr[CG];
        const float4* wqp = (const float4*)(wq + (size_t)oc * CG);
        const float4* wkp = (const float4*)(wk + (size_t)oc * CG);
        const float4* wvp = (const float4*)(wv + (size_t)oc * CG);
#pragma unroll
        for (int i = 0; i < CG / 4; ++i) {
            float4 a = wqp[i], bb = wkp[i], cc = wvp[i];
            wqr[4*i+0]=a.x; wqr[4*i+1]=a.y; wqr[4*i+2]=a.z; wqr[4*i+3]=a.w;
            wkr[4*i+0]=bb.x; wkr[4*i+1]=bb.y; wkr[4*i+2]=bb.z; wkr[4*i+3]=bb.w;
            wvr[4*i+0]=cc.x; wvr[4*i+1]=cc.y; wvr[4*i+2]=cc.z; wvr[4*i+3]=cc.w;
        }
        const float qe = qemb[oc];

#pragma unroll 1   // rolled: keeps peak liveness ~112 under the 128 cap
        for (int it = 0; it < NPIX_HALO / 8; ++it) {
            const int hp = it * 8 + p0;
            const int hi = hp / HT, hj = hp % HT;
            const float4* xp = (const float4*)&xs[hp][0];
            float aq = qe, ak = 0.f, av = 0.f;
#pragma unroll
            for (int i = 0; i < CG / 4; ++i) {
                const float4 xv = xp[i];   // LDS broadcast within half-wave
                aq = fmaf(wqr[4*i+0], xv.x, aq); ak = fmaf(wkr[4*i+0], xv.x, ak); av = fmaf(wvr[4*i+0], xv.x, av);
                aq = fmaf(wqr[4*i+1], xv.y, aq); ak = fmaf(wkr[4*i+1], xv.y, ak); av = fmaf(wvr[4*i+1], xv.y, av);
                aq = fmaf(wqr[4*i+2], xv.z, aq); ak = fmaf(wkr[4*i+2], xv.z, ak); av = fmaf(wvr[4*i+2], xv.z, av);
                aq = fmaf(wqr[4*i+3], xv.w, aq); ak = fmaf(wkr[4*i+3], xv.w, ak); av = fmaf(wvr[4*i+3], xv.w, av);
            }
            // pack k,v -> bf16 (round-half-up) in one u32; overwrite xs row
            // in place (all reads of this row happened above, same lanes).
            const unsigned kb = __float_as_uint(ak) + 0x8000u;
            const unsigned vb = __float_as_uint(av) + 0x8000u;
            ((unsigned*)&xs[hp][0])[c] = (kb >> 16) | (vb & 0xffff0000u);
            if (hi >= PAD && hi < PAD + TILE && hj >= PAD && hj < PAD + TILE)
                qs[(hi - PAD) * TILE + (hj - PAD)][c] = aq * LOG2E;
        }
    }

    // rel row for this channel (global, L2-hot) while waiting on barrier
    const float* rp = rel + (size_t)oc * 25;
    float relr[25];
#pragma unroll
    for (int i = 0; i < 25; ++i) relr[i] = rp[i];

    __syncthreads();   // merged pass -> C

    // q (already *log2e) for this thread's 8 column pixels
    float qreg[8];
#pragma unroll
    for (int ii = 0; ii < 8; ++ii) qreg[ii] = qs[ii * TILE + p0][c];

    // ---- Phase C: row-streaming attention (xs holds packed bf16 k,v).
    float s_[8], a_[8];
#pragma unroll
    for (int ii = 0; ii < 8; ++ii) { s_[ii] = 0.f; a_[ii] = 0.f; }

    const unsigned* kvp = (const unsigned*)&xs[0][0];
#pragma unroll
    for (int h = 0; h < HT; ++h) {
        float kr[5], vr[5];
#pragma unroll
        for (int j = 0; j < 5; ++j) {
            const unsigned u = kvp[(h * HT + p0 + j) * CG + c];
            kr[j] = __uint_as_float(u << 16);          // bf16 k -> f32
            vr[j] = __uint_as_float(u & 0xffff0000u);  // bf16 v -> f32
        }
#pragma unroll
        for (int ii = 0; ii < 8; ++ii) {
            const int di = h - ii;               // compile-time after unroll
            if (di >= 0 && di < 5) {
                const float qv = qreg[ii];
#pragma unroll
                for (int j = 0; j < 5; ++j) {
                    const float e = __builtin_amdgcn_exp2f(qv * (kr[j] + relr[di * 5 + j]));
                    s_[ii] += e;
                    a_[ii] = fmaf(e, vr[j], a_[ii]);
                }
            }
        }
    }

#pragma unroll
    for (int ii = 0; ii < 8; ++ii) {
        const int gh = ti * TILE + ii, gw = tj * TILE + p0;
        out[(((size_t)b * TH + gh) * TW + gw) * TC + g * CG + c] =
            a_[ii] * __builtin_amdgcn_rcpf(s_[ii]);
    }
}

extern "C" void kernel_launch(void* const* d_in, const int* in_sizes, int n_in,
                              void* d_out, int out_size, void* d_ws, size_t ws_size,
                              hipStream_t stream) {
    const float* x    = (const float*)d_in[0];
    const float* wq   = (const float*)d_in[1];
    const float* wk   = (const float*)d_in[2];
    const float* wv   = (const float*)d_in[3];
    const float* rel  = (const float*)d_in[4];
    const float* qemb = (const float*)d_in[5];
    float* out = (float*)d_out;

    const int nblocks = TB * NT * NT * G;   // 4*7*7*8 = 1568
    hipLaunchKernelGGL(fused_attn_conv_kernel, dim3(nblocks), dim3(256), 0, stream,
                       x, wq, wk, wv, rel, qemb, out);
}